// Round 1
// baseline (39.518 us; speedup 1.0000x reference)
//
#include <hip/hip_runtime.h>

#define B_    4
#define H_    8
#define T_    1024
#define D_    64
#define BH    32
#define LCH   64            // chunk length
#define NC    (T_ / LCH)    // 16 chunks
#define DECAY 0.95f
#define LDSP  68            // padded LDS row (floats) to break bank conflicts

// ---------------------------------------------------------------------------
// Kernel A: per-chunk local decayed state  L_c[d][e] = sum_j decay^(L-1-j) k_j[d] v_j[e]
// grid = BH*NC blocks of 256 threads; each thread owns 16 (d,e) elements.
// ---------------------------------------------------------------------------
__global__ __launch_bounds__(256) void kv_local(const float* __restrict__ k,
                                                const float* __restrict__ v,
                                                float* __restrict__ Lmat) {
    __shared__ float ks[LCH][LDSP];   // decay-prescaled k rows  [time][d]
    __shared__ float vs[LCH][LDSP];   // v rows                  [time][e]
    const int tid = threadIdx.x;
    const int bh  = blockIdx.x / NC;
    const int c   = blockIdx.x % NC;
    const float* kg = k + ((size_t)bh * T_ + (size_t)c * LCH) * D_;
    const float* vg = v + ((size_t)bh * T_ + (size_t)c * LCH) * D_;

    #pragma unroll
    for (int r = 0; r < 4; ++r) {
        int idx = r * 256 + tid;        // float4 index 0..1023
        int i   = idx >> 4;             // time row 0..63
        int d4  = (idx & 15) << 2;      // col 0..60
        float4 kk = *(const float4*)(kg + i * D_ + d4);
        float4 vv = *(const float4*)(vg + i * D_ + d4);
        float  sc = __powf(DECAY, (float)(LCH - 1 - i));
        kk.x *= sc; kk.y *= sc; kk.z *= sc; kk.w *= sc;
        *(float4*)&ks[i][d4] = kk;
        *(float4*)&vs[i][d4] = vv;
    }
    __syncthreads();

    const int e  = tid & 63;
    const int d0 = (tid >> 6) << 4;     // 0,16,32,48
    float s[16];
    #pragma unroll
    for (int m = 0; m < 16; ++m) s[m] = 0.f;

    for (int i = 0; i < LCH; ++i) {
        float ve = vs[i][e];
        #pragma unroll
        for (int m = 0; m < 4; ++m) {
            float4 kk = *(const float4*)&ks[i][d0 + 4 * m];   // broadcast (wave-uniform addr)
            s[4*m+0] += kk.x * ve;
            s[4*m+1] += kk.y * ve;
            s[4*m+2] += kk.z * ve;
            s[4*m+3] += kk.w * ve;
        }
    }
    float* outp = Lmat + (size_t)blockIdx.x * (D_ * D_);
    #pragma unroll
    for (int m = 0; m < 16; ++m) outp[(d0 + m) * D_ + e] = s[m];   // coalesced over e
}

// ---------------------------------------------------------------------------
// Kernel B: in-place inter-chunk scan (per (d,e) element, over 16 chunks).
// After this, slot c holds S_init(c) = state BEFORE chunk c.
// grid = BH*4096/256 = 512 blocks of 256.
// ---------------------------------------------------------------------------
__global__ __launch_bounds__(256) void kv_scan(float* __restrict__ Lmat) {
    int gid = blockIdx.x * 256 + threadIdx.x;   // 0..131071
    int bh  = gid >> 12;
    int el  = gid & 4095;
    float* p = Lmat + (size_t)bh * NC * (D_ * D_) + el;
    const float dec64 = __powf(DECAY, (float)LCH);
    float s = 0.f;
    #pragma unroll
    for (int c = 0; c < NC; ++c) {
        float tmp = p[(size_t)c * (D_ * D_)];
        p[(size_t)c * (D_ * D_)] = s;           // write S_init(c)
        s = dec64 * s + tmp;                    // -> S_end(c)
    }
}

// ---------------------------------------------------------------------------
// Kernel C: outputs.
//   A[i][j] = (q_i . k_j) * decay^(i-j)  (j<=i, else 0)
//   o_i[e]  = decay^(i+1) * sum_d q_i[d] Sinit[d][e]  +  sum_{j<=i} A[i][j] v_j[e]
// grid = BH*NC blocks of 256; thread -> row i = tid>>2, 16-col group g = tid&3.
// ---------------------------------------------------------------------------
__global__ __launch_bounds__(256) void kv_out(const float* __restrict__ q,
                                              const float* __restrict__ k,
                                              const float* __restrict__ v,
                                              const float* __restrict__ Sinit,
                                              float* __restrict__ o) {
    __shared__ float qs [LCH][LDSP];   // q rows [i][d]
    __shared__ float kts[D_ ][LDSP];   // k transposed [d][j]; reused as A[i][j]
    __shared__ float vs [LCH][LDSP];   // v rows [j][e]
    __shared__ float Ss [D_ ][LDSP];   // Sinit [d][e]
    __shared__ float dp [LCH];         // decay powers

    const int tid = threadIdx.x;
    const int bh  = blockIdx.x / NC;
    const int c   = blockIdx.x % NC;
    const size_t base = ((size_t)bh * T_ + (size_t)c * LCH) * D_;
    const float* qg = q + base;
    const float* kg = k + base;
    const float* vg = v + base;
    const float* Sg = Sinit + (size_t)blockIdx.x * (D_ * D_);

    if (tid < LCH) dp[tid] = __powf(DECAY, (float)tid);

    #pragma unroll
    for (int r = 0; r < 4; ++r) {
        int idx = r * 256 + tid;
        int i   = idx >> 4;
        int d4  = (idx & 15) << 2;
        float4 qq = *(const float4*)(qg + i * D_ + d4);
        float4 vv = *(const float4*)(vg + i * D_ + d4);
        float4 ss = *(const float4*)(Sg + i * D_ + d4);
        float4 kk = *(const float4*)(kg + i * D_ + d4);
        *(float4*)&qs[i][d4] = qq;
        *(float4*)&vs[i][d4] = vv;
        *(float4*)&Ss[i][d4] = ss;      // here i plays the role of d
        kts[d4 + 0][i] = kk.x;          // transpose k into [d][j]
        kts[d4 + 1][i] = kk.y;
        kts[d4 + 2][i] = kk.z;
        kts[d4 + 3][i] = kk.w;
    }
    __syncthreads();

    const int i  = tid >> 2;        // output/time row 0..63
    const int g  = tid & 3;
    const int j0 = g << 4;          // 16-col group (doubles as e0)

    // ---- Step 1: A[i][j0..j0+15] = (q_i . k_j) * decay^(i-j), masked causal
    float a[16];
    #pragma unroll
    for (int m = 0; m < 16; ++m) a[m] = 0.f;
    for (int d = 0; d < D_; ++d) {
        float qv = qs[i][d];
        #pragma unroll
        for (int m = 0; m < 4; ++m) {
            float4 kk = *(const float4*)&kts[d][j0 + 4 * m];
            a[4*m+0] += qv * kk.x;
            a[4*m+1] += qv * kk.y;
            a[4*m+2] += qv * kk.z;
            a[4*m+3] += qv * kk.w;
        }
    }
    #pragma unroll
    for (int m = 0; m < 16; ++m) {
        int j = j0 + m;
        a[m] = (j <= i) ? a[m] * dp[i - j] : 0.f;
    }
    __syncthreads();                     // all done reading kts
    #pragma unroll
    for (int m = 0; m < 16; ++m) kts[i][j0 + m] = a[m];   // store A over kts
    __syncthreads();

    // ---- Step 2: outputs
    float acc[16];
    #pragma unroll
    for (int m = 0; m < 16; ++m) acc[m] = 0.f;

    // part 1: decay^(i+1) * q_i @ Sinit
    for (int d = 0; d < D_; ++d) {
        float qv = qs[i][d];
        #pragma unroll
        for (int m = 0; m < 4; ++m) {
            float4 sv = *(const float4*)&Ss[d][j0 + 4 * m];
            acc[4*m+0] += qv * sv.x;
            acc[4*m+1] += qv * sv.y;
            acc[4*m+2] += qv * sv.z;
            acc[4*m+3] += qv * sv.w;
        }
    }
    const float sc = dp[i] * DECAY;      // decay^(i+1)
    #pragma unroll
    for (int m = 0; m < 16; ++m) acc[m] *= sc;

    // part 2: sum_{j<=i} A[i][j] * v_j[e]
    for (int j = 0; j <= i; ++j) {
        float av = kts[i][j];
        #pragma unroll
        for (int m = 0; m < 4; ++m) {
            float4 vv = *(const float4*)&vs[j][j0 + 4 * m];
            acc[4*m+0] += av * vv.x;
            acc[4*m+1] += av * vv.y;
            acc[4*m+2] += av * vv.z;
            acc[4*m+3] += av * vv.w;
        }
    }

    float* og = o + base + (size_t)i * D_ + j0;
    #pragma unroll
    for (int m = 0; m < 4; ++m) {
        *(float4*)(og + 4 * m) =
            make_float4(acc[4*m+0], acc[4*m+1], acc[4*m+2], acc[4*m+3]);
    }
}

// ---------------------------------------------------------------------------
extern "C" void kernel_launch(void* const* d_in, const int* in_sizes, int n_in,
                              void* d_out, int out_size, void* d_ws, size_t ws_size,
                              hipStream_t stream) {
    const float* q = (const float*)d_in[0];
    const float* k = (const float*)d_in[1];
    const float* v = (const float*)d_in[2];
    float* outp = (float*)d_out;

    const size_t scratch_bytes = (size_t)BH * NC * D_ * D_ * sizeof(float); // 8 MiB
    // Prefer d_ws; if too small, alias d_out (safe: each kv_out block reads its
    // Sinit slot fully before its post-barrier write to the identical range).
    float* scratch = (ws_size >= scratch_bytes) ? (float*)d_ws : outp;

    kv_local<<<BH * NC, 256, 0, stream>>>(k, v, scratch);
    kv_scan <<<BH * 16, 256, 0, stream>>>(scratch);
    kv_out  <<<BH * NC, 256, 0, stream>>>(q, k, v, scratch, outp);
}

// Round 2
// 23.983 us; speedup vs baseline: 1.6477x; 1.6477x over previous
//
#include <hip/hip_runtime.h>

#define B_    4
#define H_    8
#define T_    1024
#define D_    64
#define BH    32
#define LCH   64            // chunk length
#define NC    (T_ / LCH)    // 16 chunks
#define DECAY 0.95f
#define LDSB  72            // padded bf16 row (144B stride -> bank-balanced b128 frags)

typedef __attribute__((ext_vector_type(8))) short   bf8_t;   // 8 bf16 = 4 VGPRs (MFMA A/B frag)
typedef __attribute__((ext_vector_type(8))) unsigned short u16x8;
typedef __attribute__((ext_vector_type(4))) float   f32x4;
typedef unsigned short u16;

static __device__ __forceinline__ u16 f2bf(float f) {
    unsigned int u = __float_as_uint(f);
    u += 0x7fff + ((u >> 16) & 1);          // RNE
    return (u16)(u >> 16);
}

// ---------------------------------------------------------------------------
// Kernel A: per-chunk local decayed state, TRANSPOSED:
//   LT[e][d] = sum_j v_j[e] * (decay^(L-1-j) k_j[d])   ==  V^T @ K'
// MFMA: C[m=e][n=d], A[m=e][kk=j] = VT[e][j], B[kk=j][n=d] = KT[d][j].
// grid = BH*NC blocks of 256 (4 waves; wave w owns e-rows [16w,16w+16)).
// ---------------------------------------------------------------------------
__global__ __launch_bounds__(256) void kv_local(const float* __restrict__ k,
                                                const float* __restrict__ v,
                                                float* __restrict__ Lmat) {
    __shared__ u16 KT[D_][LDSB];   // K'[j][d] transposed -> [d][j]
    __shared__ u16 VT[D_][LDSB];   // V [j][e] transposed -> [e][j]
    const int tid = threadIdx.x;
    const int bh  = blockIdx.x / NC;
    const int c   = blockIdx.x % NC;
    const size_t base = ((size_t)bh * T_ + (size_t)c * LCH) * D_;
    const float* kg = k + base;
    const float* vg = v + base;

    // stage with transpose: thread t -> time row j = t>>2, 16 cols at (t&3)*16
    {
        const int j  = tid >> 2;
        const int c0 = (tid & 3) << 4;
        const float ksc = __powf(DECAY, (float)(LCH - 1 - j));
        #pragma unroll
        for (int m = 0; m < 4; ++m) {
            float4 kk = *(const float4*)(kg + j * D_ + c0 + 4 * m);
            float4 vv = *(const float4*)(vg + j * D_ + c0 + 4 * m);
            KT[c0 + 4*m + 0][j] = f2bf(kk.x * ksc);
            KT[c0 + 4*m + 1][j] = f2bf(kk.y * ksc);
            KT[c0 + 4*m + 2][j] = f2bf(kk.z * ksc);
            KT[c0 + 4*m + 3][j] = f2bf(kk.w * ksc);
            VT[c0 + 4*m + 0][j] = f2bf(vv.x);
            VT[c0 + 4*m + 1][j] = f2bf(vv.y);
            VT[c0 + 4*m + 2][j] = f2bf(vv.z);
            VT[c0 + 4*m + 3][j] = f2bf(vv.w);
        }
    }
    __syncthreads();

    const int w    = tid >> 6;
    const int lane = tid & 63;
    const int fr   = lane & 15;
    const int fk   = (lane >> 4) << 3;
    const int e0   = w << 4;

    f32x4 acc[4];
    #pragma unroll
    for (int m = 0; m < 4; ++m) acc[m] = (f32x4){0.f, 0.f, 0.f, 0.f};

    #pragma unroll
    for (int kt = 0; kt < 2; ++kt) {
        bf8_t av = *(const bf8_t*)&VT[e0 + fr][kt * 32 + fk];
        #pragma unroll
        for (int dt = 0; dt < 4; ++dt) {
            bf8_t bk = *(const bf8_t*)&KT[dt * 16 + fr][kt * 32 + fk];
            acc[dt] = __builtin_amdgcn_mfma_f32_16x16x32_bf16(av, bk, acc[dt], 0, 0, 0);
        }
    }

    // C/D layout: col = lane&15 (d within tile), row = (lane>>4)*4 + r (e within wave slab)
    float* outp = Lmat + (size_t)blockIdx.x * (D_ * D_);
    const int er = e0 + ((lane >> 4) << 2);
    #pragma unroll
    for (int dt = 0; dt < 4; ++dt)
        #pragma unroll
        for (int r = 0; r < 4; ++r)
            outp[(size_t)(er + r) * D_ + dt * 16 + fr] = acc[dt][r];
}

// ---------------------------------------------------------------------------
// Kernel B: in-place inter-chunk scan over 16 chunk slots (layout-agnostic).
// After: slot c holds S^T_init(c). grid = 512 blocks of 256.
// ---------------------------------------------------------------------------
__global__ __launch_bounds__(256) void kv_scan(float* __restrict__ Lmat) {
    int gid = blockIdx.x * 256 + threadIdx.x;   // 0..131071
    int bh  = gid >> 12;
    int el  = gid & 4095;
    float* p = Lmat + (size_t)bh * NC * (D_ * D_) + el;
    const float dec64 = __powf(DECAY, (float)LCH);
    float s = 0.f;
    #pragma unroll
    for (int c = 0; c < NC; ++c) {
        float tmp = p[(size_t)c * (D_ * D_)];
        p[(size_t)c * (D_ * D_)] = s;
        s = dec64 * s + tmp;
    }
}

// ---------------------------------------------------------------------------
// Kernel C: outputs via 3 MFMA matmuls per chunk.
//   A[i][j] = (decay^i q_i)·(decay^-j k_j), masked j<=i
//   O = decay * (Q'' @ S_init) + A @ V      (Q'' = decay^i q_i)
// wave w owns output rows i in [16w, 16w+16); causal => j-tiles jt<=w only.
// ---------------------------------------------------------------------------
__global__ __launch_bounds__(256) void kv_out(const float* __restrict__ q,
                                              const float* __restrict__ k,
                                              const float* __restrict__ v,
                                              const float* __restrict__ Sinit, // [e][d] per slot
                                              float* __restrict__ o) {
    __shared__ u16 Qs [LCH][LDSB];   // decay^i * q   [i][d]
    __shared__ u16 Ks [LCH][LDSB];   // decay^-j * k  [j][d]
    __shared__ u16 VT [D_ ][LDSB];   // v transposed  [e][j]
    __shared__ u16 STs[D_ ][LDSB];   // S^T_init bf16 [e][d]
    __shared__ u16 As [LCH][LDSB];   // masked A      [i][j]

    const int tid = threadIdx.x;
    const int bh  = blockIdx.x / NC;
    const int c   = blockIdx.x % NC;
    const size_t base = ((size_t)bh * T_ + (size_t)c * LCH) * D_;
    const float* qg = q + base;
    const float* kg = k + base;
    const float* vg = v + base;
    const float* Sg = Sinit + (size_t)blockIdx.x * (D_ * D_);

    // ---- staging: thread t -> row = t>>2, 16 cols at (t&3)*16
    {
        const int row = tid >> 2;
        const int c0  = (tid & 3) << 4;
        const float qsc = __powf(DECAY, (float)row);
        const float ksc = __powf(DECAY, -(float)row);
        u16x8 tq[2], tk[2], ts[2];
        #pragma unroll
        for (int m = 0; m < 4; ++m) {
            float4 qq = *(const float4*)(qg + row * D_ + c0 + 4 * m);
            float4 kk = *(const float4*)(kg + row * D_ + c0 + 4 * m);
            float4 ss = *(const float4*)(Sg + row * D_ + c0 + 4 * m);
            float4 vv = *(const float4*)(vg + row * D_ + c0 + 4 * m);
            const int h = m >> 1, off = (m & 1) << 2;
            tq[h][off + 0] = f2bf(qq.x * qsc); tq[h][off + 1] = f2bf(qq.y * qsc);
            tq[h][off + 2] = f2bf(qq.z * qsc); tq[h][off + 3] = f2bf(qq.w * qsc);
            tk[h][off + 0] = f2bf(kk.x * ksc); tk[h][off + 1] = f2bf(kk.y * ksc);
            tk[h][off + 2] = f2bf(kk.z * ksc); tk[h][off + 3] = f2bf(kk.w * ksc);
            ts[h][off + 0] = f2bf(ss.x);       ts[h][off + 1] = f2bf(ss.y);
            ts[h][off + 2] = f2bf(ss.z);       ts[h][off + 3] = f2bf(ss.w);
            VT[c0 + 4*m + 0][row] = f2bf(vv.x);
            VT[c0 + 4*m + 1][row] = f2bf(vv.y);
            VT[c0 + 4*m + 2][row] = f2bf(vv.z);
            VT[c0 + 4*m + 3][row] = f2bf(vv.w);
        }
        *(u16x8*)&Qs [row][c0 + 0] = tq[0];  *(u16x8*)&Qs [row][c0 + 8] = tq[1];
        *(u16x8*)&Ks [row][c0 + 0] = tk[0];  *(u16x8*)&Ks [row][c0 + 8] = tk[1];
        *(u16x8*)&STs[row][c0 + 0] = ts[0];  *(u16x8*)&STs[row][c0 + 8] = ts[1];
    }
    __syncthreads();

    const int w    = tid >> 6;          // wave id (uniform)
    const int lane = tid & 63;
    const int fr   = lane & 15;
    const int fk   = (lane >> 4) << 3;
    const int i0   = w << 4;
    const int ihi  = (lane >> 4) << 2;

    // Q fragments (reused by QK^T and Q@S)
    bf8_t aq0 = *(const bf8_t*)&Qs[i0 + fr][ 0 + fk];
    bf8_t aq1 = *(const bf8_t*)&Qs[i0 + fr][32 + fk];

    // ---- QK^T, causal tiles only
    f32x4 accA[4];
    #pragma unroll
    for (int m = 0; m < 4; ++m) accA[m] = (f32x4){0.f, 0.f, 0.f, 0.f};
    #pragma unroll
    for (int jt = 0; jt < 4; ++jt) {
        if (jt <= w) {
            bf8_t b0 = *(const bf8_t*)&Ks[jt * 16 + fr][ 0 + fk];
            bf8_t b1 = *(const bf8_t*)&Ks[jt * 16 + fr][32 + fk];
            accA[jt] = __builtin_amdgcn_mfma_f32_16x16x32_bf16(aq0, b0, accA[jt], 0, 0, 0);
            accA[jt] = __builtin_amdgcn_mfma_f32_16x16x32_bf16(aq1, b1, accA[jt], 0, 0, 0);
        }
    }

    // ---- mask + bf16 + store A (wave-private rows; same-wave DS ordering)
    #pragma unroll
    for (int jt = 0; jt < 4; ++jt) {
        #pragma unroll
        for (int r = 0; r < 4; ++r) {
            const int i  = i0 + ihi + r;
            const int jj = jt * 16 + fr;
            float val = (jt < w || (jt == w && jj <= i)) ? accA[jt][r] : 0.f;
            As[i][jj] = f2bf(val);
        }
    }

    // ---- O1 = Q'' @ S_init  (then *decay => decay^(i+1) q @ S)
    f32x4 accO[4];
    #pragma unroll
    for (int m = 0; m < 4; ++m) accO[m] = (f32x4){0.f, 0.f, 0.f, 0.f};
    #pragma unroll
    for (int et = 0; et < 4; ++et) {
        bf8_t b0 = *(const bf8_t*)&STs[et * 16 + fr][ 0 + fk];
        bf8_t b1 = *(const bf8_t*)&STs[et * 16 + fr][32 + fk];
        accO[et] = __builtin_amdgcn_mfma_f32_16x16x32_bf16(aq0, b0, accO[et], 0, 0, 0);
        accO[et] = __builtin_amdgcn_mfma_f32_16x16x32_bf16(aq1, b1, accO[et], 0, 0, 0);
    }
    #pragma unroll
    for (int et = 0; et < 4; ++et) accO[et] *= DECAY;

    // ---- O2 = A @ V  (K-slices limited by causality: ceil((w+1)/2))
    const int nk2 = (w + 2) >> 1;
    #pragma unroll
    for (int kt2 = 0; kt2 < 2; ++kt2) {
        if (kt2 < nk2) {
            bf8_t aa = *(const bf8_t*)&As[i0 + fr][kt2 * 32 + fk];
            #pragma unroll
            for (int et = 0; et < 4; ++et) {
                bf8_t bv = *(const bf8_t*)&VT[et * 16 + fr][kt2 * 32 + fk];
                accO[et] = __builtin_amdgcn_mfma_f32_16x16x32_bf16(aa, bv, accO[et], 0, 0, 0);
            }
        }
    }

    // ---- store O (coalesced 16-float segments)
    float* og = o + base;
    #pragma unroll
    for (int et = 0; et < 4; ++et)
        #pragma unroll
        for (int r = 0; r < 4; ++r)
            og[(size_t)(i0 + ihi + r) * D_ + et * 16 + fr] = accO[et][r];
}

// ---------------------------------------------------------------------------
extern "C" void kernel_launch(void* const* d_in, const int* in_sizes, int n_in,
                              void* d_out, int out_size, void* d_ws, size_t ws_size,
                              hipStream_t stream) {
    const float* q = (const float*)d_in[0];
    const float* k = (const float*)d_in[1];
    const float* v = (const float*)d_in[2];
    float* outp = (float*)d_out;

    const size_t scratch_bytes = (size_t)BH * NC * D_ * D_ * sizeof(float); // 8 MiB
    // Prefer d_ws; else alias d_out (block X's output region == scratch slot X,
    // and each block fully reads its slot (pre-barrier) before writing it).
    float* scratch = (ws_size >= scratch_bytes) ? (float*)d_ws : outp;

    kv_local<<<BH * NC, 256, 0, stream>>>(k, v, scratch);
    kv_scan <<<BH * 16, 256, 0, stream>>>(scratch);
    kv_out  <<<BH * NC, 256, 0, stream>>>(q, k, v, scratch, outp);
}

// Round 3
// 23.806 us; speedup vs baseline: 1.6600x; 1.0075x over previous
//
#include <hip/hip_runtime.h>

#define B_    4
#define H_    8
#define T_    1024
#define D_    64
#define BH    32
#define LCH   64            // chunk length
#define NC    16            // chunks per (b,h)
#define DECAY 0.95f
#define LN_D  0.051293294f  // -ln(0.95)
#define LDSB  68            // padded bf16 LDS row (kv_local transposes)
#define LDSA  68            // padded bf16 LDS row (kv_out A matrix)
#define SLOT  8192          // u16 per 16KB slot: [L/S: 4096][VT: 4096]

typedef __attribute__((ext_vector_type(8))) short          bf8_t;  // MFMA A/B frag
typedef __attribute__((ext_vector_type(8))) unsigned short u16x8;
typedef __attribute__((ext_vector_type(4))) float          f32x4;
typedef unsigned short u16;

static __device__ __forceinline__ u16 f2bf(float f) {
    unsigned int u = __float_as_uint(f);
    u += 0x7fff + ((u >> 16) & 1);          // RNE
    return (u16)(u >> 16);
}
static __device__ __forceinline__ float bf2f(u16 h) {
    return __uint_as_float(((unsigned int)h) << 16);
}
// Build a bf16 A/B fragment from 8 consecutive global fp32, scaled.
static __device__ __forceinline__ bf8_t frag_f32(const float* __restrict__ p, float sc) {
    float4 a = *(const float4*)p;
    float4 b = *(const float4*)(p + 4);
    u16x8 r;
    r[0] = f2bf(a.x * sc); r[1] = f2bf(a.y * sc); r[2] = f2bf(a.z * sc); r[3] = f2bf(a.w * sc);
    r[4] = f2bf(b.x * sc); r[5] = f2bf(b.y * sc); r[6] = f2bf(b.z * sc); r[7] = f2bf(b.w * sc);
    return __builtin_bit_cast(bf8_t, r);
}

// ---------------------------------------------------------------------------
// Kernel A: slot(bh,c) <- { L^T bf16 [e][d] (decay-weighted local state),
//                           V^T bf16 [e][j] }
// L^T[e][d] = decay^63 * sum_j v_j[e] * (decay^-j k_j[d])
// ---------------------------------------------------------------------------
__global__ __launch_bounds__(256) void kv_local(const float* __restrict__ k,
                                                const float* __restrict__ v,
                                                u16* __restrict__ scr) {
    __shared__ u16 KT[D_][LDSB];   // decay^-j k, transposed [d][j]
    __shared__ u16 VT[D_][LDSB];   // v transposed [e][j]
    const int tid = threadIdx.x;
    const int bh  = blockIdx.x / NC;
    const int c   = blockIdx.x % NC;
    const size_t base = ((size_t)bh * T_ + (size_t)c * LCH) * D_;
    const float* kg = k + base;
    const float* vg = v + base;

    {   // stage + transpose: thread t -> time row j = t>>2, 16 cols at (t&3)*16
        const int j  = tid >> 2;
        const int c0 = (tid & 3) << 4;
        const float ksc = __expf(LN_D * (float)j);   // decay^-j
        #pragma unroll
        for (int m = 0; m < 4; ++m) {
            float4 kk = *(const float4*)(kg + j * D_ + c0 + 4 * m);
            float4 vv = *(const float4*)(vg + j * D_ + c0 + 4 * m);
            KT[c0 + 4*m + 0][j] = f2bf(kk.x * ksc);
            KT[c0 + 4*m + 1][j] = f2bf(kk.y * ksc);
            KT[c0 + 4*m + 2][j] = f2bf(kk.z * ksc);
            KT[c0 + 4*m + 3][j] = f2bf(kk.w * ksc);
            VT[c0 + 4*m + 0][j] = f2bf(vv.x);
            VT[c0 + 4*m + 1][j] = f2bf(vv.y);
            VT[c0 + 4*m + 2][j] = f2bf(vv.z);
            VT[c0 + 4*m + 3][j] = f2bf(vv.w);
        }
    }
    __syncthreads();

    const int lane = tid & 63, w = tid >> 6;
    const int fr   = lane & 15;
    const int fk   = (lane >> 4) << 3;
    const int e0   = w << 4;

    f32x4 acc[4];
    #pragma unroll
    for (int m = 0; m < 4; ++m) acc[m] = (f32x4){0.f, 0.f, 0.f, 0.f};
    #pragma unroll
    for (int kt = 0; kt < 2; ++kt) {
        bf8_t av = *(const bf8_t*)&VT[e0 + fr][kt * 32 + fk];
        #pragma unroll
        for (int dt = 0; dt < 4; ++dt) {
            bf8_t bk = *(const bf8_t*)&KT[dt * 16 + fr][kt * 32 + fk];
            acc[dt] = __builtin_amdgcn_mfma_f32_16x16x32_bf16(av, bk, acc[dt], 0, 0, 0);
        }
    }

    u16* slot = scr + (size_t)blockIdx.x * SLOT;
    const float dec63 = __powf(DECAY, 63.f);
    const int er = e0 + ((lane >> 4) << 2);
    #pragma unroll
    for (int dt = 0; dt < 4; ++dt)
        #pragma unroll
        for (int r = 0; r < 4; ++r)
            slot[(er + r) * D_ + dt * 16 + fr] = f2bf(acc[dt][r] * dec63);

    {   // dump V^T (already transposed in LDS) -> slot, coalesced
        const int e  = tid >> 2;
        const int j0 = (tid & 3) << 4;
        u16* dst = slot + 4096 + e * D_ + j0;
        *(u16x8*)(dst + 0) = *(const u16x8*)&VT[e][j0 + 0];
        *(u16x8*)(dst + 8) = *(const u16x8*)&VT[e][j0 + 8];
    }
}

// ---------------------------------------------------------------------------
// Kernel B: inter-chunk scan on L (bf16, in regs). After: slot c holds S_init(c).
// Thread owns 8 consecutive elements across all 16 chunks of one bh.
// grid = 32 bh * 512 groups / 256 = 64 blocks.
// ---------------------------------------------------------------------------
__global__ __launch_bounds__(256) void kv_scan(u16* __restrict__ scr) {
    const int gid = blockIdx.x * 256 + threadIdx.x;   // 0..16383
    const int bh  = gid >> 9;
    const int e8  = (gid & 511) << 3;
    u16* base = scr + (size_t)bh * NC * SLOT + e8;

    u16x8 t[16];
    #pragma unroll
    for (int c = 0; c < NC; ++c) t[c] = *(const u16x8*)(base + (size_t)c * SLOT);

    const float dec64 = __powf(DECAY, 64.f);
    float s[8];
    #pragma unroll
    for (int e = 0; e < 8; ++e) s[e] = 0.f;
    #pragma unroll
    for (int c = 0; c < NC; ++c) {
        u16x8 out;
        #pragma unroll
        for (int e = 0; e < 8; ++e) {
            float f = bf2f(t[c][e]);
            out[e]  = f2bf(s[e]);
            s[e]    = dec64 * s[e] + f;
        }
        *(u16x8*)(base + (size_t)c * SLOT) = out;
    }
}

// ---------------------------------------------------------------------------
// Kernel C: O = decay^{i+1} (q_i @ S_init) + sum_{j<=i} decay^{i-j}(q_i.k_j) v_j
// No big staging: Q/K frags straight from global fp32 (on-the-fly bf16+scale),
// S/V^T frags straight from bf16 slot. Only A matrix in LDS (wave-private,
// zero barriers).
// ---------------------------------------------------------------------------
__global__ __launch_bounds__(256) void kv_out(const float* __restrict__ q,
                                              const float* __restrict__ k,
                                              const u16* __restrict__ scr,
                                              float* __restrict__ o) {
    __shared__ u16 As[LCH][LDSA];
    const int tid = threadIdx.x;
    const int bh  = blockIdx.x / NC;
    const int c   = blockIdx.x % NC;
    const size_t base = ((size_t)bh * T_ + (size_t)c * LCH) * D_;
    const u16* Ssl = scr + (size_t)blockIdx.x * SLOT;          // S_init^T [e][d]
    const u16* Vsl = Ssl + 4096;                               // V^T      [e][j]

    const int lane = tid & 63, w = tid >> 6;
    const int fr   = lane & 15, hi = lane >> 4;
    const int fk   = hi << 3;
    const int i0   = w << 4;
    const int ib   = i0 + (hi << 2);          // this lane's 4 output rows

    // A-operand: raw q rows -> bf16 (decay^i deferred)
    const float* qrow = q + base + (size_t)(i0 + fr) * D_;
    const bf8_t aq0 = frag_f32(qrow + fk, 1.f);
    const bf8_t aq1 = frag_f32(qrow + 32 + fk, 1.f);

    // ---- QK^T (K scaled by decay^-j on the fly), causal tiles only
    f32x4 accA[4];
    #pragma unroll
    for (int m = 0; m < 4; ++m) accA[m] = (f32x4){0.f, 0.f, 0.f, 0.f};
    #pragma unroll
    for (int jt = 0; jt < 4; ++jt) {
        if (jt <= w) {
            const int j = jt * 16 + fr;
            const float* krow = k + base + (size_t)j * D_;
            const float ksc = __expf(LN_D * (float)j);     // decay^-j
            bf8_t b0 = frag_f32(krow + fk, ksc);
            bf8_t b1 = frag_f32(krow + 32 + fk, ksc);
            accA[jt] = __builtin_amdgcn_mfma_f32_16x16x32_bf16(aq0, b0, accA[jt], 0, 0, 0);
            accA[jt] = __builtin_amdgcn_mfma_f32_16x16x32_bf16(aq1, b1, accA[jt], 0, 0, 0);
        }
    }

    // per-row decay^i scales
    const float db = __expf(-LN_D * (float)ib);            // decay^ib
    float isc[4];
    isc[0] = db; isc[1] = db * DECAY; isc[2] = isc[1] * DECAY; isc[3] = isc[2] * DECAY;

    // ---- mask + scale + store A (wave-private rows, no barrier needed)
    #pragma unroll
    for (int jt = 0; jt < 4; ++jt)
        #pragma unroll
        for (int r = 0; r < 4; ++r) {
            const int i  = ib + r;
            const int jj = jt * 16 + fr;
            float val = (jj <= i) ? accA[jt][r] * isc[r] : 0.f;
            As[i][jj] = f2bf(val);
        }

    // ---- O1 = q @ S_init (B-frags: direct 16B bf16 loads from slot)
    f32x4 accO[4];
    #pragma unroll
    for (int m = 0; m < 4; ++m) accO[m] = (f32x4){0.f, 0.f, 0.f, 0.f};
    #pragma unroll
    for (int et = 0; et < 4; ++et) {
        bf8_t b0 = *(const bf8_t*)(Ssl + (et * 16 + fr) * D_ + fk);
        bf8_t b1 = *(const bf8_t*)(Ssl + (et * 16 + fr) * D_ + 32 + fk);
        accO[et] = __builtin_amdgcn_mfma_f32_16x16x32_bf16(aq0, b0, accO[et], 0, 0, 0);
        accO[et] = __builtin_amdgcn_mfma_f32_16x16x32_bf16(aq1, b1, accO[et], 0, 0, 0);
    }
    #pragma unroll
    for (int et = 0; et < 4; ++et)
        #pragma unroll
        for (int r = 0; r < 4; ++r)
            accO[et][r] *= isc[r] * DECAY;                 // decay^{i+1}

    // ---- O2 += A @ V  (causal K-slices)
    const int nk2 = (w + 2) >> 1;
    #pragma unroll
    for (int kt2 = 0; kt2 < 2; ++kt2) {
        if (kt2 < nk2) {
            bf8_t aa = *(const bf8_t*)&As[i0 + fr][kt2 * 32 + fk];
            #pragma unroll
            for (int et = 0; et < 4; ++et) {
                bf8_t bv = *(const bf8_t*)(Vsl + (et * 16 + fr) * D_ + kt2 * 32 + fk);
                accO[et] = __builtin_amdgcn_mfma_f32_16x16x32_bf16(aa, bv, accO[et], 0, 0, 0);
            }
        }
    }

    // ---- store O
    float* og = o + base;
    #pragma unroll
    for (int et = 0; et < 4; ++et)
        #pragma unroll
        for (int r = 0; r < 4; ++r)
            og[(size_t)(ib + r) * D_ + et * 16 + fr] = accO[et][r];
}

// ---------------------------------------------------------------------------
extern "C" void kernel_launch(void* const* d_in, const int* in_sizes, int n_in,
                              void* d_out, int out_size, void* d_ws, size_t ws_size,
                              hipStream_t stream) {
    const float* q = (const float*)d_in[0];
    const float* k = (const float*)d_in[1];
    const float* v = (const float*)d_in[2];
    float* outp = (float*)d_out;

    const size_t scratch_bytes = (size_t)BH * NC * SLOT * sizeof(u16);  // 8.39 MB
    // Slot (bh,c) is byte-identical to block (bh,c)'s O region, and every block
    // reads only its own slot before (dataflow-ordered) writing O -> aliasing
    // d_out is safe when d_ws is too small.
    u16* scr = (ws_size >= scratch_bytes) ? (u16*)d_ws : (u16*)outp;

    kv_local<<<BH * NC, 256, 0, stream>>>(k, v, scr);
    kv_scan <<<64,      256, 0, stream>>>(scr);
    kv_out  <<<BH * NC, 256, 0, stream>>>(q, k, scr, outp);
}